// Round 1
// baseline (599.625 us; speedup 1.0000x reference)
//
#include <hip/hip_runtime.h>
#include <hip/hip_bf16.h>

// ---------------- problem constants ----------------
#define B_    256
#define T_    250
#define NIN   700
#define NHID  512
#define NOUT  20
#define NSEG  4
#define KT_PER_SEG 22            // ceil(700/32) -> padded K per segment = 704
#define M_TOT (B_ * T_)          // 64000

typedef float  f32x4  __attribute__((ext_vector_type(4)));
typedef __bf16 bf16x8 __attribute__((ext_vector_type(8)));

// ---------------- workspace layout ----------------
// [0, 131,072,000)                : i_in  (M_TOT x NHID f32)
// [131,072,000, +2,883,584)       : Bpack (4*22*512*32 bf16), tile-order [seg][kt][h][kk]
// [.., +1,048,576)                : w_recT (512x512 f32, w_recT[hp][h] = w_rec[h][hp])
#define IIN_BYTES   ((size_t)M_TOT * NHID * 4)
#define BPACK_ELEMS (NSEG * KT_PER_SEG * NHID * 32)   // 1,441,792
#define BPACK_OFF   IIN_BYTES
#define WRECT_OFF   (BPACK_OFF + (size_t)BPACK_ELEMS * 2)

__device__ __forceinline__ void async_copy16(const void* g, void* l) {
    __builtin_amdgcn_global_load_lds(
        (const __attribute__((address_space(1))) unsigned int*)g,
        (__attribute__((address_space(3))) unsigned int*)l, 16, 0, 0);
}

// ---------------- kernel 1: pack B (fp32 -> bf16, MFMA tile order) + transpose w_rec ----------------
__global__ __launch_bounds__(256) void kan_pack(
    const float* __restrict__ w_kan, const float* __restrict__ d1,
    const float* __restrict__ d2,    const float* __restrict__ d3,
    const float* __restrict__ w_rec,
    __bf16* __restrict__ Bpack, float* __restrict__ wrecT)
{
    int idx = blockIdx.x * 256 + threadIdx.x;
    if (idx < BPACK_ELEMS) {
        int kk  = idx & 31;
        int h   = (idx >> 5) & 511;
        int sk  = idx >> 14;           // seg*22 + kt
        int kt  = sk % 22;
        int seg = sk / 22;
        int k   = kt * 32 + kk;
        const float* w = (seg == 0) ? w_kan : (seg == 1) ? d1 : (seg == 2) ? d2 : d3;
        float v = (k < NIN) ? w[(size_t)h * NIN + k] : 0.0f;
        Bpack[idx] = (__bf16)v;
    }
    if (idx < NHID * NHID) {
        int h  = idx & 511;
        int hp = idx >> 9;
        wrecT[(size_t)hp * NHID + h] = w_rec[(size_t)h * NHID + hp];
    }
}

// ---------------- kernel 2: i_in = [x|t1|t1^2|t1^3] @ [w_kan|d1|d2|d3]^T (bf16 MFMA) ----------------
// 128x128 block tile, BK=32, 4 waves (2x2 of 64x64), 16x16x32 bf16 MFMA.
__global__ __launch_bounds__(256, 2) void kan_gemm(
    const float* __restrict__ x, const __bf16* __restrict__ Bpack,
    float* __restrict__ iin)
{
    __shared__ __align__(16) __bf16 sA[128 * 32];
    __shared__ __align__(16) __bf16 sB[128 * 32];

    const int tid  = threadIdx.x;
    const int lane = tid & 63;
    const int wave = tid >> 6;
    const int wm   = wave >> 1;
    const int wn   = wave & 1;
    const int mtile = blockIdx.x * 128;
    const int ntile = blockIdx.y * 128;

    const int arow  = tid >> 1;            // 0..127 (A row staged by this thread)
    const int ahalf = (tid & 1) * 16;      // k-offset 0 or 16
    const float* xrow = x + (size_t)(mtile + arow) * NIN;

    const int quad = lane >> 4;
    const int l16  = lane & 15;
    const int k8   = quad * 8;

    f32x4 acc[4][4];
    #pragma unroll
    for (int i = 0; i < 4; ++i)
        #pragma unroll
        for (int j = 0; j < 4; ++j)
            acc[i][j] = (f32x4){0.f, 0.f, 0.f, 0.f};

    #pragma unroll 1
    for (int kt = 0; kt < KT_PER_SEG; ++kt) {
        // load this thread's 16 x-values once per k-tile (guarded, 16B-aligned float4s)
        float xv[16], tv[16];
        #pragma unroll
        for (int q = 0; q < 4; ++q) {
            int k = kt * 32 + ahalf + q * 4;
            f32x4 v = {0.f, 0.f, 0.f, 0.f};
            if (k < NIN) v = *(const f32x4*)(xrow + k);
            xv[q * 4 + 0] = v[0]; xv[q * 4 + 1] = v[1];
            xv[q * 4 + 2] = v[2]; xv[q * 4 + 3] = v[3];
        }
        #pragma unroll
        for (int e = 0; e < 16; ++e) tv[e] = fminf(fabsf(xv[e]), 1.0f);

        #pragma unroll
        for (int seg = 0; seg < NSEG; ++seg) {
            __syncthreads();   // previous step's LDS reads complete

            // B tile (8 KB, contiguous) via async global->LDS, width 16
            {
                const char* gB = (const char*)(Bpack +
                    ((size_t)(seg * KT_PER_SEG + kt) * NHID + ntile) * 32);
                int off = wave * 1024 + lane * 16;
                async_copy16(gB + off,        ((char*)sB) + off);
                async_copy16(gB + off + 4096, ((char*)sB) + off + 4096);
            }

            // A tile: transform + convert + ds_write_b128 x2
            bf16x8 p0, p1;
            #pragma unroll
            for (int e = 0; e < 8; ++e) {
                float a0, a1v;
                if (seg == 0)      { a0 = xv[e];                 a1v = xv[e + 8]; }
                else if (seg == 1) { a0 = tv[e];                 a1v = tv[e + 8]; }
                else if (seg == 2) { a0 = tv[e] * tv[e];         a1v = tv[e + 8] * tv[e + 8]; }
                else               { a0 = tv[e] * tv[e] * tv[e]; a1v = tv[e + 8] * tv[e + 8] * tv[e + 8]; }
                p0[e] = (__bf16)a0;
                p1[e] = (__bf16)a1v;
            }
            *(bf16x8*)(&sA[arow * 32 + ahalf])     = p0;
            *(bf16x8*)(&sA[arow * 32 + ahalf + 8]) = p1;

            __syncthreads();

            bf16x8 af[4], bfr[4];
            #pragma unroll
            for (int i = 0; i < 4; ++i)
                af[i] = *(const bf16x8*)(&sA[(wm * 64 + i * 16 + l16) * 32 + k8]);
            #pragma unroll
            for (int j = 0; j < 4; ++j)
                bfr[j] = *(const bf16x8*)(&sB[(wn * 64 + j * 16 + l16) * 32 + k8]);

            #pragma unroll
            for (int i = 0; i < 4; ++i)
                #pragma unroll
                for (int j = 0; j < 4; ++j)
                    acc[i][j] = __builtin_amdgcn_mfma_f32_16x16x32_bf16(
                        af[i], bfr[j], acc[i][j], 0, 0, 0);
        }
    }

    // epilogue: C/D layout col=lane&15, row=quad*4+reg  [guide §3, m89-verified]
    #pragma unroll
    for (int i = 0; i < 4; ++i) {
        int m0 = mtile + wm * 64 + i * 16 + quad * 4;
        #pragma unroll
        for (int j = 0; j < 4; ++j) {
            int h0 = ntile + wn * 64 + j * 16 + l16;
            #pragma unroll
            for (int r = 0; r < 4; ++r)
                iin[(size_t)(m0 + r) * NHID + h0] = acc[i][j][r];
        }
    }
}

// ---------------- kernel 3: adaptive-LIF scan, one block per batch sample ----------------
__global__ __launch_bounds__(512) void kan_scan(
    const float* __restrict__ iin, const float* __restrict__ wrecT,
    const float* __restrict__ w_out, float* __restrict__ out)
{
    const int b    = blockIdx.x;
    const int h    = threadIdx.x;     // hidden unit
    const int lane = h & 63;
    const int wave = h >> 6;

    __shared__ unsigned long long smask[8];
    __shared__ float s1f[NHID];
    __shared__ float siout[NOUT];

    float v1 = 0.f, a1 = 0.f, s1 = 0.f;
    float v_out = 0.f, acco = 0.f;    // used by threads h < NOUT

    const float* base = iin + (size_t)b * T_ * NHID + h;

    // 8-deep prefetch pipeline (register shift queue)
    float q0 = base[0 * NHID], q1 = base[1 * NHID], q2 = base[2 * NHID], q3 = base[3 * NHID],
          q4 = base[4 * NHID], q5 = base[5 * NHID], q6 = base[6 * NHID], q7 = base[7 * NHID];

    unsigned long long pmask[8];
    #pragma unroll
    for (int w = 0; w < 8; ++w) pmask[w] = 0ull;
    int pcount = 0;

    #pragma unroll 1
    for (int t = 0; t < T_; ++t) {
        float cur = q0;
        q0 = q1; q1 = q2; q2 = q3; q3 = q4; q4 = q5; q5 = q6; q6 = q7;
        int tn = t + 8;
        float nl = 0.f;
        if (tn < T_) nl = base[(size_t)tn * NHID];
        q7 = nl;

        // recurrent input from previous step's spikes (bitmask-sparse)
        float i1 = cur;
        if (pcount > 0) {
            #pragma unroll 1
            for (int w = 0; w < 8; ++w) {
                unsigned long long m = pmask[w];
                while (m) {
                    int bit = __ffsll(m) - 1;
                    m &= m - 1;
                    i1 += wrecT[(size_t)(w * 64 + bit) * NHID + h];
                }
            }
        }

        // adaptive LIF (s1 here is the PREVIOUS spike, per reference ordering)
        v1 = 0.95f * v1 + 0.05f * i1 - 1.0f * s1;
        a1 = 0.85f * a1 + 0.15f * s1;
        float sn = (v1 - (1.0f + 0.05f * a1)) > 0.0f ? 1.0f : 0.0f;
        s1 = sn;

        unsigned long long bal = __ballot(sn > 0.0f);
        s1f[h] = sn;
        if (lane == 0) smask[wave] = bal;
        __syncthreads();

        int cnt = 0;
        #pragma unroll
        for (int w = 0; w < 8; ++w) { pmask[w] = smask[w]; cnt += __popcll(pmask[w]); }
        pcount = cnt;

        // readout: i_out = s1 @ w_out.T (dense reduction, only when spikes exist)
        if (cnt > 0) {                       // block-uniform branch
            for (int o = wave; o < NOUT; o += 8) {
                float part = 0.f;
                #pragma unroll
                for (int kk = 0; kk < 8; ++kk)
                    part += s1f[lane + kk * 64] * w_out[(size_t)o * NHID + lane + kk * 64];
                #pragma unroll
                for (int d = 32; d >= 1; d >>= 1) part += __shfl_down(part, d);
                if (lane == 0) siout[o] = part;
            }
            __syncthreads();
        }

        if (h < NOUT) {
            float io = (cnt > 0) ? siout[h] : 0.0f;
            v_out = 0.9f * v_out + io;
            float so = (v_out - 1.0f) > 0.0f ? 1.0f : 0.0f;
            v_out -= 1.0f * so;
            acco += v_out;                   // reference records post-reset v_out
        }
        __syncthreads();                     // protect s1f/smask before next step's writes
    }

    if (h < NOUT) out[b * NOUT + h] = acco / 250.0f;
}

// ---------------- launcher ----------------
extern "C" void kernel_launch(void* const* d_in, const int* in_sizes, int n_in,
                              void* d_out, int out_size, void* d_ws, size_t ws_size,
                              hipStream_t stream)
{
    const float* x     = (const float*)d_in[0];
    const float* w_kan = (const float*)d_in[1];
    const float* d1    = (const float*)d_in[2];
    const float* d2    = (const float*)d_in[3];
    const float* d3    = (const float*)d_in[4];
    const float* w_rec = (const float*)d_in[5];
    const float* w_out = (const float*)d_in[6];
    float* out = (float*)d_out;

    char*   ws    = (char*)d_ws;
    float*  iin   = (float*)ws;
    __bf16* Bpack = (__bf16*)(ws + BPACK_OFF);
    float*  wrecT = (float*)(ws + WRECT_OFF);

    kan_pack<<<dim3((BPACK_ELEMS + 255) / 256), 256, 0, stream>>>(
        w_kan, d1, d2, d3, w_rec, Bpack, wrecT);
    kan_gemm<<<dim3(M_TOT / 128, NHID / 128), 256, 0, stream>>>(x, Bpack, iin);
    kan_scan<<<dim3(B_), 512, 0, stream>>>(iin, wrecT, w_out, out);
}

// Round 2
// 591.210 us; speedup vs baseline: 1.0142x; 1.0142x over previous
//
#include <hip/hip_runtime.h>
#include <hip/hip_bf16.h>

// ---------------- problem constants ----------------
#define B_    256
#define T_    250
#define NIN   700
#define NHID  512
#define NOUT  20
#define NSEG  4
#define KT_PER_SEG 22            // ceil(700/32) -> padded K per segment = 704
#define M_TOT (B_ * T_)          // 64000

typedef float  f32x4  __attribute__((ext_vector_type(4)));
typedef __bf16 bf16x8 __attribute__((ext_vector_type(8)));

// ---------------- workspace layout ----------------
#define IIN_BYTES   ((size_t)M_TOT * NHID * 4)
#define BPACK_ELEMS (NSEG * KT_PER_SEG * NHID * 32)   // 1,441,792
#define BPACK_OFF   IIN_BYTES
#define WRECT_OFF   (BPACK_OFF + (size_t)BPACK_ELEMS * 2)

__device__ __forceinline__ void async_copy16(const void* g, void* l) {
    __builtin_amdgcn_global_load_lds(
        (const __attribute__((address_space(1))) unsigned int*)g,
        (__attribute__((address_space(3))) unsigned int*)l, 16, 0, 0);
}

// ---------------- kernel 1: pack B (fp32->bf16, MFMA tile order, XOR-chunk-swizzled) ----------------
// LDS row r holds chunks in order chunk' = chunk ^ ((r>>1)&3); since global_load_lds
// is a linear lane->chunk DMA, we realize the swizzle by permuting the SOURCE order here.
__global__ __launch_bounds__(256) void kan_pack(
    const float* __restrict__ w_kan, const float* __restrict__ d1,
    const float* __restrict__ d2,    const float* __restrict__ d3,
    const float* __restrict__ w_rec,
    __bf16* __restrict__ Bpack, float* __restrict__ wrecT)
{
    int idx = blockIdx.x * 256 + threadIdx.x;
    if (idx < BPACK_ELEMS) {
        int kk  = idx & 31;            // destination position within LDS row
        int h   = (idx >> 5) & 511;
        int sk  = idx >> 14;           // seg*22 + kt
        int kt  = sk % 22;
        int seg = sk / 22;
        int c_lds = kk >> 3;
        int e     = kk & 7;
        int c_src = c_lds ^ ((h >> 1) & 3);   // XOR swizzle (tile rows are 128-aligned)
        int k   = kt * 32 + c_src * 8 + e;
        const float* w = (seg == 0) ? w_kan : (seg == 1) ? d1 : (seg == 2) ? d2 : d3;
        float v = (k < NIN) ? w[(size_t)h * NIN + k] : 0.0f;
        Bpack[idx] = (__bf16)v;
    }
    if (idx < NHID * NHID) {
        int h  = idx & 511;
        int hp = idx >> 9;
        wrecT[(size_t)hp * NHID + h] = w_rec[(size_t)h * NHID + hp];
    }
}

// ---------------- kernel 2: i_in = [x|t1|t1^2|t1^3] @ [w_kan|d1|d2|d3]^T (bf16 MFMA) ----------------
// 128x128 block tile, BK=32, 4 waves (2x2 of 64x64), 16x16x32 bf16 MFMA.
// grid = (ntiles=4, mtiles=500): consecutive blocks share the x m-tile -> L3 absorbs re-reads.
__global__ __launch_bounds__(256, 2) void kan_gemm(
    const float* __restrict__ x, const __bf16* __restrict__ Bpack,
    float* __restrict__ iin)
{
    __shared__ __align__(16) __bf16 sA[128 * 32];
    __shared__ __align__(16) __bf16 sB[128 * 32];

    const int tid  = threadIdx.x;
    const int lane = tid & 63;
    const int wave = tid >> 6;
    const int wm   = wave >> 1;
    const int wn   = wave & 1;
    const int mtile = blockIdx.y * 128;
    const int ntile = blockIdx.x * 128;

    const int arow  = tid >> 1;            // 0..127 (A row staged by this thread)
    const int ahalf = (tid & 1) * 16;      // k-offset 0 or 16 elements
    const int fA    = (arow >> 1) & 3;     // row swizzle for staged writes
    const int c0    = (tid & 1) * 2;       // source chunk of p0
    const float* xrow = x + (size_t)(mtile + arow) * NIN;

    const int quad = lane >> 4;
    const int l16  = lane & 15;
    const int fr   = (l16 >> 1) & 3;       // row swizzle for fragment reads
    const int cq   = (quad ^ fr) * 8;      // swizzled chunk element offset

    f32x4 acc[4][4];
    #pragma unroll
    for (int i = 0; i < 4; ++i)
        #pragma unroll
        for (int j = 0; j < 4; ++j)
            acc[i][j] = (f32x4){0.f, 0.f, 0.f, 0.f};

    #pragma unroll 1
    for (int kt = 0; kt < KT_PER_SEG; ++kt) {
        float xv[16], tv[16];
        #pragma unroll
        for (int q = 0; q < 4; ++q) {
            int k = kt * 32 + ahalf + q * 4;
            f32x4 v = {0.f, 0.f, 0.f, 0.f};
            if (k < NIN) v = *(const f32x4*)(xrow + k);
            xv[q * 4 + 0] = v[0]; xv[q * 4 + 1] = v[1];
            xv[q * 4 + 2] = v[2]; xv[q * 4 + 3] = v[3];
        }
        #pragma unroll
        for (int e = 0; e < 16; ++e) tv[e] = fminf(fabsf(xv[e]), 1.0f);

        #pragma unroll
        for (int seg = 0; seg < NSEG; ++seg) {
            __syncthreads();   // previous step's LDS reads complete

            // B tile (8 KB, pre-swizzled in Bpack) via async global->LDS, width 16
            {
                const char* gB = (const char*)(Bpack +
                    ((size_t)(seg * KT_PER_SEG + kt) * NHID + ntile) * 32);
                int off = wave * 1024 + lane * 16;
                async_copy16(gB + off,        ((char*)sB) + off);
                async_copy16(gB + off + 4096, ((char*)sB) + off + 4096);
            }

            // A tile: transform + convert + 2x ds_write_b128 (XOR-swizzled chunks)
            bf16x8 p0, p1;
            #pragma unroll
            for (int e = 0; e < 8; ++e) {
                float a0, a1v;
                if (seg == 0)      { a0 = xv[e];                 a1v = xv[e + 8]; }
                else if (seg == 1) { a0 = tv[e];                 a1v = tv[e + 8]; }
                else if (seg == 2) { a0 = tv[e] * tv[e];         a1v = tv[e + 8] * tv[e + 8]; }
                else               { a0 = tv[e] * tv[e] * tv[e]; a1v = tv[e + 8] * tv[e + 8] * tv[e + 8]; }
                p0[e] = (__bf16)a0;
                p1[e] = (__bf16)a1v;
            }
            *(bf16x8*)(&sA[arow * 32 + ((c0     ^ fA) * 8)]) = p0;
            *(bf16x8*)(&sA[arow * 32 + (((c0+1) ^ fA) * 8)]) = p1;

            __syncthreads();

            bf16x8 af[4], bfr[4];
            #pragma unroll
            for (int i = 0; i < 4; ++i)
                af[i] = *(const bf16x8*)(&sA[(wm * 64 + i * 16 + l16) * 32 + cq]);
            #pragma unroll
            for (int j = 0; j < 4; ++j)
                bfr[j] = *(const bf16x8*)(&sB[(wn * 64 + j * 16 + l16) * 32 + cq]);

            #pragma unroll
            for (int i = 0; i < 4; ++i)
                #pragma unroll
                for (int j = 0; j < 4; ++j)
                    acc[i][j] = __builtin_amdgcn_mfma_f32_16x16x32_bf16(
                        af[i], bfr[j], acc[i][j], 0, 0, 0);
        }
    }

    // epilogue: C/D layout col=lane&15, row=quad*4+reg  [guide §3, m89-verified]
    #pragma unroll
    for (int i = 0; i < 4; ++i) {
        int m0 = mtile + wm * 64 + i * 16 + quad * 4;
        #pragma unroll
        for (int j = 0; j < 4; ++j) {
            int h0 = ntile + wn * 64 + j * 16 + l16;
            #pragma unroll
            for (int r = 0; r < 4; ++r)
                iin[(size_t)(m0 + r) * NHID + h0] = acc[i][j][r];
        }
    }
}

// ---------------- kernel 3: adaptive-LIF scan, ONE WAVE per batch sample ----------------
// lane owns 8 hidden units; all cross-unit traffic is __ballot / wave-uniform.
// No barriers, no LDS -> global loads stay in flight across steps.
#define PF 5   // prefetch depth; T_=250 = 50*PF so static queue slots via unroll
__global__ __launch_bounds__(64) void kan_scan(
    const float* __restrict__ iin, const float* __restrict__ wrecT,
    const float* __restrict__ w_out, float* __restrict__ out)
{
    const int b    = blockIdx.x;
    const int lane = threadIdx.x;
    const float* base = iin + (size_t)b * T_ * NHID + lane * 8;

    f32x4 qa[PF], qb[PF];
    #pragma unroll
    for (int d = 0; d < PF; ++d) {
        qa[d] = *(const f32x4*)(base + (size_t)d * NHID);
        qb[d] = *(const f32x4*)(base + (size_t)d * NHID + 4);
    }

    float v1[8], a1[8];
    #pragma unroll
    for (int u = 0; u < 8; ++u) { v1[u] = 0.f; a1[u] = 0.f; }
    unsigned sm = 0;          // own 8 spike bits (previous step)
    int anyprev = 0;          // wave-uniform: any spike in wave last step
    float v_out = 0.f, acco = 0.f;

    #pragma unroll 1
    for (int t0 = 0; t0 < T_; t0 += PF) {
        #pragma unroll
        for (int j = 0; j < PF; ++j) {
            const int t = t0 + j;
            float cur[8];
            cur[0] = qa[j][0]; cur[1] = qa[j][1]; cur[2] = qa[j][2]; cur[3] = qa[j][3];
            cur[4] = qb[j][0]; cur[5] = qb[j][1]; cur[6] = qb[j][2]; cur[7] = qb[j][3];
            if (t + PF < T_) {                 // refill static slot j for step t+PF
                qa[j] = *(const f32x4*)(base + (size_t)(t + PF) * NHID);
                qb[j] = *(const f32x4*)(base + (size_t)(t + PF) * NHID + 4);
            }

            // recurrent input from previous step's spikes (wave-uniform rare path)
            if (anyprev) {
                #pragma unroll
                for (int u = 0; u < 8; ++u) {
                    unsigned long long mu = __ballot((sm >> u) & 1u);
                    while (mu) {
                        int jl = __ffsll(mu) - 1; mu &= mu - 1;
                        const float* wr = wrecT + (size_t)(jl * 8 + u) * NHID + lane * 8;
                        f32x4 wa = *(const f32x4*)wr;
                        f32x4 wb = *(const f32x4*)(wr + 4);
                        cur[0] += wa[0]; cur[1] += wa[1]; cur[2] += wa[2]; cur[3] += wa[3];
                        cur[4] += wb[0]; cur[5] += wb[1]; cur[6] += wb[2]; cur[7] += wb[3];
                    }
                }
            }

            // adaptive LIF (sm = previous spikes, per reference ordering)
            unsigned nm = 0;
            #pragma unroll
            for (int u = 0; u < 8; ++u) {
                float sp = ((sm >> u) & 1u) ? 1.0f : 0.0f;
                v1[u] = 0.95f * v1[u] + 0.05f * cur[u] - sp;
                a1[u] = 0.85f * a1[u] + 0.15f * sp;
                if (v1[u] - (1.0f + 0.05f * a1[u]) > 0.0f) nm |= (1u << u);
            }

            unsigned long long anyb = __ballot(nm != 0u);
            float io = 0.0f;
            if (anyb) {      // wave-uniform rare path: readout current from spikes
                #pragma unroll
                for (int u = 0; u < 8; ++u) {
                    unsigned long long mu = __ballot((nm >> u) & 1u);
                    while (mu) {
                        int jl = __ffsll(mu) - 1; mu &= mu - 1;
                        int unit = jl * 8 + u;
                        if (lane < NOUT) io += w_out[(size_t)lane * NHID + unit];
                    }
                }
            }

            // readout LIF (lane = output index; lanes >= NOUT stay at 0)
            v_out = 0.9f * v_out + io;
            float so = (v_out - 1.0f > 0.0f) ? 1.0f : 0.0f;
            v_out -= so;
            acco += v_out;

            sm = nm;
            anyprev = (anyb != 0ull);
        }
    }

    if (lane < NOUT) out[b * NOUT + lane] = acco * (1.0f / 250.0f);
}

// ---------------- launcher ----------------
extern "C" void kernel_launch(void* const* d_in, const int* in_sizes, int n_in,
                              void* d_out, int out_size, void* d_ws, size_t ws_size,
                              hipStream_t stream)
{
    const float* x     = (const float*)d_in[0];
    const float* w_kan = (const float*)d_in[1];
    const float* d1    = (const float*)d_in[2];
    const float* d2    = (const float*)d_in[3];
    const float* d3    = (const float*)d_in[4];
    const float* w_rec = (const float*)d_in[5];
    const float* w_out = (const float*)d_in[6];
    float* out = (float*)d_out;

    char*   ws    = (char*)d_ws;
    float*  iin   = (float*)ws;
    __bf16* Bpack = (__bf16*)(ws + BPACK_OFF);
    float*  wrecT = (float*)(ws + WRECT_OFF);

    kan_pack<<<dim3((BPACK_ELEMS + 255) / 256), 256, 0, stream>>>(
        w_kan, d1, d2, d3, w_rec, Bpack, wrecT);
    kan_gemm<<<dim3(NHID / 128, M_TOT / 128), 256, 0, stream>>>(x, Bpack, iin);
    kan_scan<<<dim3(B_), 64, 0, stream>>>(iin, wrecT, w_out, out);
}

// Round 3
// 555.944 us; speedup vs baseline: 1.0786x; 1.0634x over previous
//
#include <hip/hip_runtime.h>
#include <hip/hip_bf16.h>

// ---------------- problem constants ----------------
#define B_    256
#define T_    250
#define NIN   700
#define NHID  512
#define NOUT  20
#define NSEG  4
#define KT_N  11                 // k-tiles of 64 per segment: 704 = 11*64
#define M_TOT (B_ * T_)          // 64000

typedef float  f32x4  __attribute__((ext_vector_type(4)));
typedef float  f32x16 __attribute__((ext_vector_type(16)));
typedef int    i32x8  __attribute__((ext_vector_type(8)));

// ---------------- workspace layout ----------------
// [0, 131,072,000)        : i_in  (M_TOT x NHID f32)
// [+0, +1,441,792)        : Bpack fp8, fragment-major (see below)
// [.., +1,048,576)        : w_recT (512x512 f32)
#define IIN_BYTES   ((size_t)M_TOT * NHID * 4)
#define BPACK_BYTES ((size_t)NSEG * KT_N * 16 * 64 * 32)   // 1,441,792
#define BPACK_WORDS (BPACK_BYTES / 4)                      // 360,448
#define BPACK_OFF   IIN_BYTES
#define WRECT_OFF   (BPACK_OFF + BPACK_BYTES)

// Bpack fragment-major layout: chunk c = ((seg*11+kt)*16 + nt32)*64 + kh*32 + ln
// chunk = 32 bytes; byte jj of chunk = fp8(W_seg[nt32*32+ln][kt*64+kh*32+jj]), 0 if k>=700.
// A wave's B-fragment load (32 lanes x 32B) is then 1024B contiguous.

// ---------------- kernel 1: pack B to fp8 fragment-major + transpose w_rec ----------------
__global__ __launch_bounds__(256) void kan_pack(
    const float* __restrict__ w_kan, const float* __restrict__ d1,
    const float* __restrict__ d2,    const float* __restrict__ d3,
    const float* __restrict__ w_rec,
    int* __restrict__ BpackW, float* __restrict__ wrecT)
{
    int idx = blockIdx.x * 256 + threadIdx.x;
    if (idx < (int)BPACK_WORDS) {
        int w   = idx;
        int c   = w >> 3;                  // 32-byte chunk index
        int jj  = (w & 7) * 4;             // byte offset within chunk
        int ln  = c & 31;
        int kh  = (c >> 5) & 1;
        int nt  = (c >> 6) & 15;
        int ks  = c >> 10;                 // seg*11 + kt
        int kt  = ks % 11;
        int seg = ks / 11;
        int n   = nt * 32 + ln;
        int kb  = kt * 64 + kh * 32 + jj;
        const float* wp = (seg == 0) ? w_kan : (seg == 1) ? d1 : (seg == 2) ? d2 : d3;
        float f0 = (kb + 0 < NIN) ? wp[(size_t)n * NIN + kb + 0] : 0.0f;
        float f1 = (kb + 1 < NIN) ? wp[(size_t)n * NIN + kb + 1] : 0.0f;
        float f2 = (kb + 2 < NIN) ? wp[(size_t)n * NIN + kb + 2] : 0.0f;
        float f3 = (kb + 3 < NIN) ? wp[(size_t)n * NIN + kb + 3] : 0.0f;
        int u = __builtin_amdgcn_cvt_pk_fp8_f32(f0, f1, 0, false);
        u     = __builtin_amdgcn_cvt_pk_fp8_f32(f2, f3, u, true);
        BpackW[w] = u;
    }
    if (idx < NHID * NHID) {
        int h  = idx & 511;
        int hp = idx >> 9;
        wrecT[(size_t)hp * NHID + h] = w_rec[(size_t)h * NHID + hp];
    }
}

// ---------------- kernel 2: barrier-free MX-fp8 GEMM ----------------
// i_in = [x|t1|t1^2|t1^3] @ [w_kan|d1|d2|d3]^T via mfma_scale_f32_32x32x64_f8f6f4.
// Block 128x128, 4 waves (2x2 of 64x64), each wave 2x2 of 32x32 tiles.
// No LDS, no __syncthreads: A built per-lane in registers, B loaded per-lane from
// L2-resident fragment-major Bpack. grid=(4 ntiles, 500 mtiles) for x L3 reuse.
__global__ __launch_bounds__(256, 2) void kan_gemm(
    const float* __restrict__ x, const int* __restrict__ Bpack,
    float* __restrict__ iin)
{
    const int tid  = threadIdx.x;
    const int lane = tid & 63;
    const int wave = tid >> 6;
    const int wm   = wave >> 1;
    const int wn   = wave & 1;
    const int mtile = blockIdx.y * 128;
    const int ntile = blockIdx.x * 128;
    const int l31  = lane & 31;
    const int kh32 = (lane >> 5) * 32;          // k-offset within BK=64
    const int ntb  = blockIdx.x * 4 + wn * 2;   // global n-chunk (of 32) for j=0
    const int lanew = (kh32 + l31) * 8;         // word offset of this lane's chunk

    const float* xrow0 = x + (size_t)(mtile + wm * 64 +      l31) * NIN;
    const float* xrow1 = x + (size_t)(mtile + wm * 64 + 32 + l31) * NIN;

    f32x16 acc[2][2];
    #pragma unroll
    for (int i = 0; i < 2; ++i)
        #pragma unroll
        for (int j = 0; j < 2; ++j)
            #pragma unroll
            for (int r = 0; r < 16; ++r)
                acc[i][j][r] = 0.0f;

    #pragma unroll 1
    for (int kt = 0; kt < KT_N; ++kt) {
        // ---- load this lane's 2x32 x-values (guarded only at the ragged tail) ----
        float xv0[32], xv1[32];
        #pragma unroll
        for (int q = 0; q < 8; ++q) {
            int k0 = kt * 64 + kh32 + q * 4;
            f32x4 v0 = {0.f, 0.f, 0.f, 0.f}, v1 = {0.f, 0.f, 0.f, 0.f};
            if (k0 < NIN) {            // k0<700 => k0<=696, vector load stays in-row
                v0 = *(const f32x4*)(xrow0 + k0);
                v1 = *(const f32x4*)(xrow1 + k0);
            }
            #pragma unroll
            for (int t = 0; t < 4; ++t) { xv0[q * 4 + t] = v0[t]; xv1[q * 4 + t] = v1[t]; }
        }

        // ---- 4 spline segments: build A frags in regs, B frags from L2, MFMA ----
        #pragma unroll
        for (int seg = 0; seg < NSEG; ++seg) {
            if (seg == 1) {           // after raw-x segment, clip in place: t1
                #pragma unroll
                for (int e = 0; e < 32; ++e) {
                    xv0[e] = fminf(fabsf(xv0[e]), 1.0f);
                    xv1[e] = fminf(fabsf(xv1[e]), 1.0f);
                }
            }
            i32x8 a0, a1;
            #pragma unroll
            for (int w8 = 0; w8 < 8; ++w8) {
                float f00, f01, f02, f03, f10, f11, f12, f13;
                #pragma unroll
                for (int t = 0; t < 4; ++t) {
                    float e0 = xv0[w8 * 4 + t], e1 = xv1[w8 * 4 + t];
                    float g0, g1;
                    if      (seg <= 1) { g0 = e0;           g1 = e1; }
                    else if (seg == 2) { g0 = e0 * e0;      g1 = e1 * e1; }
                    else               { g0 = e0 * e0 * e0; g1 = e1 * e1 * e1; }
                    if (t == 0) { f00 = g0; f10 = g1; }
                    if (t == 1) { f01 = g0; f11 = g1; }
                    if (t == 2) { f02 = g0; f12 = g1; }
                    if (t == 3) { f03 = g0; f13 = g1; }
                }
                int u0 = __builtin_amdgcn_cvt_pk_fp8_f32(f00, f01, 0, false);
                u0     = __builtin_amdgcn_cvt_pk_fp8_f32(f02, f03, u0, true);
                int u1 = __builtin_amdgcn_cvt_pk_fp8_f32(f10, f11, 0, false);
                u1     = __builtin_amdgcn_cvt_pk_fp8_f32(f12, f13, u1, true);
                a0[w8] = u0;
                a1[w8] = u1;
            }

            const int* bp = Bpack + ((size_t)((seg * KT_N + kt) * 16 + ntb) * 512 + lanew);
            i32x8 b0 = *(const i32x8*)bp;
            i32x8 b1 = *(const i32x8*)(bp + 512);

            // scales all 1.0 (E8M0 127); cbsz=0/blgp=0 => fp8 e4m3 A and B
            acc[0][0] = __builtin_amdgcn_mfma_scale_f32_32x32x64_f8f6f4(
                a0, b0, acc[0][0], 0, 0, 0, 0x7f7f7f7f, 0, 0x7f7f7f7f);
            acc[0][1] = __builtin_amdgcn_mfma_scale_f32_32x32x64_f8f6f4(
                a0, b1, acc[0][1], 0, 0, 0, 0x7f7f7f7f, 0, 0x7f7f7f7f);
            acc[1][0] = __builtin_amdgcn_mfma_scale_f32_32x32x64_f8f6f4(
                a1, b0, acc[1][0], 0, 0, 0, 0x7f7f7f7f, 0, 0x7f7f7f7f);
            acc[1][1] = __builtin_amdgcn_mfma_scale_f32_32x32x64_f8f6f4(
                a1, b1, acc[1][1], 0, 0, 0, 0x7f7f7f7f, 0, 0x7f7f7f7f);
        }
    }

    // ---- epilogue: 32x32 C/D layout col=lane&31, row=(reg&3)+8*(reg>>2)+4*(lane>>5) ----
    #pragma unroll
    for (int i = 0; i < 2; ++i) {
        int m0 = mtile + wm * 64 + i * 32 + (kh32 >> 3);   // + kh*4
        #pragma unroll
        for (int j = 0; j < 2; ++j) {
            int c = ntile + wn * 64 + j * 32 + l31;
            #pragma unroll
            for (int r = 0; r < 16; ++r) {
                int row = m0 + (r & 3) + 8 * (r >> 2);
                iin[(size_t)row * NHID + c] = acc[i][j][r];
            }
        }
    }
}

// ---------------- kernel 3: adaptive-LIF scan, ONE WAVE per batch sample ----------------
#define PF 5
__global__ __launch_bounds__(64) void kan_scan(
    const float* __restrict__ iin, const float* __restrict__ wrecT,
    const float* __restrict__ w_out, float* __restrict__ out)
{
    const int b    = blockIdx.x;
    const int lane = threadIdx.x;
    const float* base = iin + (size_t)b * T_ * NHID + lane * 8;

    f32x4 qa[PF], qb[PF];
    #pragma unroll
    for (int d = 0; d < PF; ++d) {
        qa[d] = *(const f32x4*)(base + (size_t)d * NHID);
        qb[d] = *(const f32x4*)(base + (size_t)d * NHID + 4);
    }

    float v1[8], a1[8];
    #pragma unroll
    for (int u = 0; u < 8; ++u) { v1[u] = 0.f; a1[u] = 0.f; }
    unsigned sm = 0;
    int anyprev = 0;
    float v_out = 0.f, acco = 0.f;

    #pragma unroll 1
    for (int t0 = 0; t0 < T_; t0 += PF) {
        #pragma unroll
        for (int j = 0; j < PF; ++j) {
            const int t = t0 + j;
            float cur[8];
            cur[0] = qa[j][0]; cur[1] = qa[j][1]; cur[2] = qa[j][2]; cur[3] = qa[j][3];
            cur[4] = qb[j][0]; cur[5] = qb[j][1]; cur[6] = qb[j][2]; cur[7] = qb[j][3];
            if (t + PF < T_) {
                qa[j] = *(const f32x4*)(base + (size_t)(t + PF) * NHID);
                qb[j] = *(const f32x4*)(base + (size_t)(t + PF) * NHID + 4);
            }

            if (anyprev) {           // rare path: recurrent input from prev spikes
                #pragma unroll
                for (int u = 0; u < 8; ++u) {
                    unsigned long long mu = __ballot((sm >> u) & 1u);
                    while (mu) {
                        int jl = __ffsll(mu) - 1; mu &= mu - 1;
                        const float* wr = wrecT + (size_t)(jl * 8 + u) * NHID + lane * 8;
                        f32x4 wa = *(const f32x4*)wr;
                        f32x4 wb = *(const f32x4*)(wr + 4);
                        cur[0] += wa[0]; cur[1] += wa[1]; cur[2] += wa[2]; cur[3] += wa[3];
                        cur[4] += wb[0]; cur[5] += wb[1]; cur[6] += wb[2]; cur[7] += wb[3];
                    }
                }
            }

            unsigned nm = 0;
            #pragma unroll
            for (int u = 0; u < 8; ++u) {
                float sp = ((sm >> u) & 1u) ? 1.0f : 0.0f;
                v1[u] = 0.95f * v1[u] + 0.05f * cur[u] - sp;
                a1[u] = 0.85f * a1[u] + 0.15f * sp;
                if (v1[u] - (1.0f + 0.05f * a1[u]) > 0.0f) nm |= (1u << u);
            }

            unsigned long long anyb = __ballot(nm != 0u);
            float io = 0.0f;
            if (anyb) {              // rare path: readout current from spikes
                #pragma unroll
                for (int u = 0; u < 8; ++u) {
                    unsigned long long mu = __ballot((nm >> u) & 1u);
                    while (mu) {
                        int jl = __ffsll(mu) - 1; mu &= mu - 1;
                        int unit = jl * 8 + u;
                        if (lane < NOUT) io += w_out[(size_t)lane * NHID + unit];
                    }
                }
            }

            v_out = 0.9f * v_out + io;
            float so = (v_out - 1.0f > 0.0f) ? 1.0f : 0.0f;
            v_out -= so;
            acco += v_out;

            sm = nm;
            anyprev = (anyb != 0ull);
        }
    }

    if (lane < NOUT) out[b * NOUT + lane] = acco * (1.0f / 250.0f);
}

// ---------------- launcher ----------------
extern "C" void kernel_launch(void* const* d_in, const int* in_sizes, int n_in,
                              void* d_out, int out_size, void* d_ws, size_t ws_size,
                              hipStream_t stream)
{
    const float* x     = (const float*)d_in[0];
    const float* w_kan = (const float*)d_in[1];
    const float* d1    = (const float*)d_in[2];
    const float* d2    = (const float*)d_in[3];
    const float* d3    = (const float*)d_in[4];
    const float* w_rec = (const float*)d_in[5];
    const float* w_out = (const float*)d_in[6];
    float* out = (float*)d_out;

    char*  ws    = (char*)d_ws;
    float* iin   = (float*)ws;
    int*   Bpack = (int*)(ws + BPACK_OFF);
    float* wrecT = (float*)(ws + WRECT_OFF);

    kan_pack<<<dim3((BPACK_WORDS + 255) / 256), 256, 0, stream>>>(
        w_kan, d1, d2, d3, w_rec, Bpack, wrecT);
    kan_gemm<<<dim3(NHID / 128, M_TOT / 128), 256, 0, stream>>>(x, Bpack, iin);
    kan_scan<<<dim3(B_), 64, 0, stream>>>(iin, wrecT, w_out, out);
}

// Round 4
// 437.049 us; speedup vs baseline: 1.3720x; 1.2720x over previous
//
#include <hip/hip_runtime.h>
#include <hip/hip_bf16.h>

// ---------------- problem constants ----------------
#define B_    256
#define T_    250
#define NIN   700
#define NHID  512
#define NOUT  20
#define KT_N  11                 // k-tiles of 64 per segment: 704 = 11*64
#define MC_N  2000               // 64000 / 32 row-chunks
#define M_TOT (B_ * T_)          // 64000

typedef float  f32x2  __attribute__((ext_vector_type(2)));
typedef float  f32x4  __attribute__((ext_vector_type(4)));
typedef float  f32x16 __attribute__((ext_vector_type(16)));
typedef int    i32x4  __attribute__((ext_vector_type(4)));
typedef int    i32x8  __attribute__((ext_vector_type(8)));

// ---------------- workspace layout ----------------
// [0, 65,536,000)   : i_in  (M_TOT x NHID bf16)
// [+, 45,056,000)   : Apack fp8 fragment-major (x only; 11*2000 blocks of 2048B)
// [+, 1,441,792)    : Bpack fp8 fragment-major (4 segs)
// [+, 1,048,576)    : w_recT (512x512 f32)
#define IIN_BYTES   ((size_t)M_TOT * NHID * 2)
#define APACK_OFF   IIN_BYTES
#define APACK_BYTES ((size_t)KT_N * MC_N * 2048)
#define BPACK_OFF   (APACK_OFF + APACK_BYTES)
#define BPACK_BYTES ((size_t)4 * KT_N * 16 * 64 * 32)
#define BPACK_WORDS (BPACK_BYTES / 4)                  // 360,448
#define WRECT_OFF   (BPACK_OFF + BPACK_BYTES)

// ---------------- kernel 1: pack B to fp8 fragment-major + transpose w_rec ----------------
__global__ __launch_bounds__(256) void kan_pack(
    const float* __restrict__ w_kan, const float* __restrict__ d1,
    const float* __restrict__ d2,    const float* __restrict__ d3,
    const float* __restrict__ w_rec,
    int* __restrict__ BpackW, float* __restrict__ wrecT)
{
    int idx = blockIdx.x * 256 + threadIdx.x;
    if (idx < (int)BPACK_WORDS) {
        int w   = idx;
        int c   = w >> 3;                  // 32-byte chunk index
        int jj  = (w & 7) * 4;             // byte offset within chunk
        int ln  = c & 31;
        int kh  = (c >> 5) & 1;
        int nt  = (c >> 6) & 15;
        int ks  = c >> 10;                 // seg*11 + kt
        int kt  = ks % 11;
        int seg = ks / 11;
        int n   = nt * 32 + ln;
        int kb  = kt * 64 + kh * 32 + jj;
        const float* wp = (seg == 0) ? w_kan : (seg == 1) ? d1 : (seg == 2) ? d2 : d3;
        float f0 = (kb + 0 < NIN) ? wp[(size_t)n * NIN + kb + 0] : 0.0f;
        float f1 = (kb + 1 < NIN) ? wp[(size_t)n * NIN + kb + 1] : 0.0f;
        float f2 = (kb + 2 < NIN) ? wp[(size_t)n * NIN + kb + 2] : 0.0f;
        float f3 = (kb + 3 < NIN) ? wp[(size_t)n * NIN + kb + 3] : 0.0f;
        int u = __builtin_amdgcn_cvt_pk_fp8_f32(f0, f1, 0, false);
        u     = __builtin_amdgcn_cvt_pk_fp8_f32(f2, f3, u, true);
        BpackW[w] = u;
    }
    if (idx < NHID * NHID) {
        int h  = idx & 511;
        int hp = idx >> 9;
        wrecT[(size_t)hp * NHID + h] = w_rec[(size_t)h * NHID + hp];
    }
}

// ---------------- kernel 2: pack x to fp8 A-fragment-major ----------------
// Block = one (mc, kt): 32 rows x 64 k. Thread t=(kh,r,q) reads 8 floats coalesced-ish,
// writes 8 fp8 bytes at block_byte_offset = t*8 (fully coalesced store).
__global__ __launch_bounds__(256) void kan_packa(
    const float* __restrict__ x, int* __restrict__ Apack)
{
    int blk = blockIdx.x;          // mc*11 + kt
    int kt  = blk % KT_N;
    int mc  = blk / KT_N;
    int t   = threadIdx.x;
    int q   = t & 3;
    int r   = (t >> 2) & 31;
    int kh  = t >> 7;
    int k0  = kt * 64 + kh * 32 + q * 8;      // max 696
    const float* xr = x + (size_t)(mc * 32 + r) * NIN + k0;
    f32x4 v0 = *(const f32x4*)xr;             // always in-range (k0+3 <= 699)
    f32x4 v1 = {0.f, 0.f, 0.f, 0.f};
    if (k0 + 7 < NIN) v1 = *(const f32x4*)(xr + 4);
    int u0 = __builtin_amdgcn_cvt_pk_fp8_f32(v0[0], v0[1], 0, false);
    u0     = __builtin_amdgcn_cvt_pk_fp8_f32(v0[2], v0[3], u0, true);
    int u1 = __builtin_amdgcn_cvt_pk_fp8_f32(v1[0], v1[1], 0, false);
    u1     = __builtin_amdgcn_cvt_pk_fp8_f32(v1[2], v1[3], u1, true);
    int* dst = Apack + ((size_t)kt * MC_N + mc) * 512 + t * 2;
    dst[0] = u0;
    dst[1] = u1;
}

// ---------------- kernel 3: barrier-free fp8 GEMM, A from fragment-major pack ----------------
// i_in = [x|t1|t1^2|t1^3] @ [w_kan|d1|d2|d3]^T via mfma_scale_f32_32x32x64_f8f6f4.
// Block 128x128, 4 waves (2x2 of 64x64), wave = 2x2 of 32x32x64.
// seg0 A-frag used straight from Apack; t1/t2/t3 frags derived in registers.
__global__ __launch_bounds__(256, 2) void kan_gemm(
    const int* __restrict__ Apack, const int* __restrict__ Bpack,
    __bf16* __restrict__ iin)
{
    const int tid  = threadIdx.x;
    const int lane = tid & 63;
    const int wave = tid >> 6;
    const int wm   = wave >> 1;
    const int wn   = wave & 1;
    const int mtile = blockIdx.y * 128;
    const int ntile = blockIdx.x * 128;
    const int l31  = lane & 31;
    const int kh   = lane >> 5;
    const int mc0  = blockIdx.y * 4 + wm * 2;
    const int ntb  = blockIdx.x * 4 + wn * 2;
    const int lanew = (kh * 32 + l31) * 8;    // word offset of this lane's 32B chunk

    f32x16 acc[2][2];
    #pragma unroll
    for (int i = 0; i < 2; ++i)
        #pragma unroll
        for (int j = 0; j < 2; ++j)
            #pragma unroll
            for (int r = 0; r < 16; ++r)
                acc[i][j][r] = 0.0f;

    #pragma unroll 1
    for (int kt = 0; kt < KT_N; ++kt) {
        // ---- A seg0 fragments: one coalesced 32B load per row-block ----
        const int* ab = Apack + ((size_t)kt * MC_N + mc0) * 512 + lanew;
        i32x8 a0p = *(const i32x8*)ab;
        i32x8 a1p = *(const i32x8*)(ab + 512);

        const int* bb = Bpack + ((size_t)kt * 16 + ntb) * 512 + lanew;
        #define BSEG (KT_N * 16 * 512)        // 90112 words per seg

        // ---- seg0 (raw x) ----
        {
            i32x8 b0 = *(const i32x8*)bb;
            i32x8 b1 = *(const i32x8*)(bb + 512);
            acc[0][0] = __builtin_amdgcn_mfma_scale_f32_32x32x64_f8f6f4(
                a0p, b0, acc[0][0], 0, 0, 0, 0x7f7f7f7f, 0, 0x7f7f7f7f);
            acc[0][1] = __builtin_amdgcn_mfma_scale_f32_32x32x64_f8f6f4(
                a0p, b1, acc[0][1], 0, 0, 0, 0x7f7f7f7f, 0, 0x7f7f7f7f);
            acc[1][0] = __builtin_amdgcn_mfma_scale_f32_32x32x64_f8f6f4(
                a1p, b0, acc[1][0], 0, 0, 0, 0x7f7f7f7f, 0, 0x7f7f7f7f);
            acc[1][1] = __builtin_amdgcn_mfma_scale_f32_32x32x64_f8f6f4(
                a1p, b1, acc[1][1], 0, 0, 0, 0x7f7f7f7f, 0, 0x7f7f7f7f);
        }

        // ---- decode fp8 x -> t1 = min(|x|,1) per lane's 2x32 elements ----
        float t0r[32], t1r[32];
        #pragma unroll
        for (int w = 0; w < 8; ++w) {
            f32x2 lo = __builtin_amdgcn_cvt_pk_f32_fp8(a0p[w], false);
            f32x2 hi = __builtin_amdgcn_cvt_pk_f32_fp8(a0p[w], true);
            t0r[w * 4 + 0] = fminf(fabsf(lo[0]), 1.0f);
            t0r[w * 4 + 1] = fminf(fabsf(lo[1]), 1.0f);
            t0r[w * 4 + 2] = fminf(fabsf(hi[0]), 1.0f);
            t0r[w * 4 + 3] = fminf(fabsf(hi[1]), 1.0f);
            f32x2 lo1 = __builtin_amdgcn_cvt_pk_f32_fp8(a1p[w], false);
            f32x2 hi1 = __builtin_amdgcn_cvt_pk_f32_fp8(a1p[w], true);
            t1r[w * 4 + 0] = fminf(fabsf(lo1[0]), 1.0f);
            t1r[w * 4 + 1] = fminf(fabsf(lo1[1]), 1.0f);
            t1r[w * 4 + 2] = fminf(fabsf(hi1[0]), 1.0f);
            t1r[w * 4 + 3] = fminf(fabsf(hi1[1]), 1.0f);
        }

        // ---- segs 1..3: pack power-of-t1 fragments, load B, MFMA ----
        #pragma unroll
        for (int seg = 1; seg < 4; ++seg) {
            i32x8 a0s, a1s;
            #pragma unroll
            for (int w = 0; w < 8; ++w) {
                float g[4], h[4];
                #pragma unroll
                for (int e = 0; e < 4; ++e) {
                    float t0 = t0r[w * 4 + e], t1v = t1r[w * 4 + e];
                    if (seg == 1)      { g[e] = t0;            h[e] = t1v; }
                    else if (seg == 2) { g[e] = t0 * t0;       h[e] = t1v * t1v; }
                    else               { g[e] = t0 * t0 * t0;  h[e] = t1v * t1v * t1v; }
                }
                int u0 = __builtin_amdgcn_cvt_pk_fp8_f32(g[0], g[1], 0, false);
                u0     = __builtin_amdgcn_cvt_pk_fp8_f32(g[2], g[3], u0, true);
                int u1 = __builtin_amdgcn_cvt_pk_fp8_f32(h[0], h[1], 0, false);
                u1     = __builtin_amdgcn_cvt_pk_fp8_f32(h[2], h[3], u1, true);
                a0s[w] = u0;
                a1s[w] = u1;
            }
            const int* bs = bb + seg * BSEG;
            i32x8 b0 = *(const i32x8*)bs;
            i32x8 b1 = *(const i32x8*)(bs + 512);
            acc[0][0] = __builtin_amdgcn_mfma_scale_f32_32x32x64_f8f6f4(
                a0s, b0, acc[0][0], 0, 0, 0, 0x7f7f7f7f, 0, 0x7f7f7f7f);
            acc[0][1] = __builtin_amdgcn_mfma_scale_f32_32x32x64_f8f6f4(
                a0s, b1, acc[0][1], 0, 0, 0, 0x7f7f7f7f, 0, 0x7f7f7f7f);
            acc[1][0] = __builtin_amdgcn_mfma_scale_f32_32x32x64_f8f6f4(
                a1s, b0, acc[1][0], 0, 0, 0, 0x7f7f7f7f, 0, 0x7f7f7f7f);
            acc[1][1] = __builtin_amdgcn_mfma_scale_f32_32x32x64_f8f6f4(
                a1s, b1, acc[1][1], 0, 0, 0, 0x7f7f7f7f, 0, 0x7f7f7f7f);
        }
    }

    // ---- epilogue: 32x32 C/D layout col=lane&31, row=(r&3)+8*(r>>2)+4*(lane>>5) ----
    #pragma unroll
    for (int i = 0; i < 2; ++i) {
        int m0 = mtile + wm * 64 + i * 32 + kh * 4;
        #pragma unroll
        for (int j = 0; j < 2; ++j) {
            int c = ntile + wn * 64 + j * 32 + l31;
            #pragma unroll
            for (int r = 0; r < 16; ++r) {
                int row = m0 + (r & 3) + 8 * (r >> 2);
                iin[(size_t)row * NHID + c] = (__bf16)acc[i][j][r];
            }
        }
    }
}

// ---------------- kernel 4: adaptive-LIF scan, one wave per sample, PF=25 bf16 ----------------
#define PF 25
__global__ __launch_bounds__(64) void kan_scan(
    const __bf16* __restrict__ iin, const float* __restrict__ wrecT,
    const float* __restrict__ w_out, float* __restrict__ out)
{
    const int b    = blockIdx.x;
    const int lane = threadIdx.x;
    const __bf16* basep = iin + (size_t)b * T_ * NHID + lane * 8;
    #define LOADQ(t) (*(const i32x4*)(basep + (size_t)(t) * NHID))

    i32x4 q[PF];
    #pragma unroll
    for (int d = 0; d < PF; ++d) q[d] = LOADQ(d);

    float v1[8], a1[8];
    #pragma unroll
    for (int u = 0; u < 8; ++u) { v1[u] = 0.f; a1[u] = 0.f; }
    unsigned sm = 0;
    int anyprev = 0;
    float v_out = 0.f, acco = 0.f;

    #pragma unroll 1
    for (int t0 = 0; t0 < T_; t0 += PF) {
        #pragma unroll
        for (int j = 0; j < PF; ++j) {
            const int t = t0 + j;
            float cur[8];
            #pragma unroll
            for (int w = 0; w < 4; ++w) {
                int wv = q[j][w];
                cur[2 * w]     = __builtin_bit_cast(float, wv << 16);
                cur[2 * w + 1] = __builtin_bit_cast(float, wv & 0xffff0000);
            }
            if (t + PF < T_) q[j] = LOADQ(t + PF);

            if (anyprev) {           // rare path: recurrent input from prev spikes
                #pragma unroll
                for (int u = 0; u < 8; ++u) {
                    unsigned long long mu = __ballot((sm >> u) & 1u);
                    while (mu) {
                        int jl = __ffsll(mu) - 1; mu &= mu - 1;
                        const float* wr = wrecT + (size_t)(jl * 8 + u) * NHID + lane * 8;
                        f32x4 wa = *(const f32x4*)wr;
                        f32x4 wb = *(const f32x4*)(wr + 4);
                        cur[0] += wa[0]; cur[1] += wa[1]; cur[2] += wa[2]; cur[3] += wa[3];
                        cur[4] += wb[0]; cur[5] += wb[1]; cur[6] += wb[2]; cur[7] += wb[3];
                    }
                }
            }

            unsigned nm = 0;
            #pragma unroll
            for (int u = 0; u < 8; ++u) {
                float sp = ((sm >> u) & 1u) ? 1.0f : 0.0f;
                v1[u] = 0.95f * v1[u] + 0.05f * cur[u] - sp;
                a1[u] = 0.85f * a1[u] + 0.15f * sp;
                if (v1[u] - (1.0f + 0.05f * a1[u]) > 0.0f) nm |= (1u << u);
            }

            unsigned long long anyb = __ballot(nm != 0u);
            float io = 0.0f;
            if (anyb) {              // rare path: readout current from spikes
                #pragma unroll
                for (int u = 0; u < 8; ++u) {
                    unsigned long long mu = __ballot((nm >> u) & 1u);
                    while (mu) {
                        int jl = __ffsll(mu) - 1; mu &= mu - 1;
                        int unit = jl * 8 + u;
                        if (lane < NOUT) io += w_out[(size_t)lane * NHID + unit];
                    }
                }
            }

            v_out = 0.9f * v_out + io;
            float so = (v_out - 1.0f > 0.0f) ? 1.0f : 0.0f;
            v_out -= so;
            acco += v_out;

            sm = nm;
            anyprev = (anyb != 0ull);
        }
    }

    if (lane < NOUT) out[b * NOUT + lane] = acco * (1.0f / 250.0f);
}

// ---------------- launcher ----------------
extern "C" void kernel_launch(void* const* d_in, const int* in_sizes, int n_in,
                              void* d_out, int out_size, void* d_ws, size_t ws_size,
                              hipStream_t stream)
{
    const float* x     = (const float*)d_in[0];
    const float* w_kan = (const float*)d_in[1];
    const float* d1    = (const float*)d_in[2];
    const float* d2    = (const float*)d_in[3];
    const float* d3    = (const float*)d_in[4];
    const float* w_rec = (const float*)d_in[5];
    const float* w_out = (const float*)d_in[6];
    float* out = (float*)d_out;

    char*   ws    = (char*)d_ws;
    __bf16* iin   = (__bf16*)ws;
    int*    Apack = (int*)(ws + APACK_OFF);
    int*    Bpack = (int*)(ws + BPACK_OFF);
    float*  wrecT = (float*)(ws + WRECT_OFF);

    kan_pack<<<dim3((BPACK_WORDS + 255) / 256), 256, 0, stream>>>(
        w_kan, d1, d2, d3, w_rec, Bpack, wrecT);
    kan_packa<<<dim3(MC_N * KT_N), 256, 0, stream>>>(x, Apack);
    kan_gemm<<<dim3(NHID / 128, M_TOT / 128), 256, 0, stream>>>(Apack, Bpack, iin);
    kan_scan<<<dim3(B_), 64, 0, stream>>>(iin, wrecT, w_out, out);
}